// Round 1
// baseline (207.941 us; speedup 1.0000x reference)
//
#include <hip/hip_runtime.h>

#define B_SZ 4096
#define N_IN 4096
#define N_CTX 512
#define UNITS 4096
#define RANK 256

typedef __attribute__((ext_vector_type(8))) __bf16 bf16x8;
typedef __attribute__((ext_vector_type(4))) float f32x4;
typedef __attribute__((ext_vector_type(8))) unsigned short ushort8;
typedef __attribute__((ext_vector_type(4))) unsigned short ushort4v;

__device__ __forceinline__ unsigned short f2bf(float f) {
    unsigned int u = __float_as_uint(f);
    u += 0x7FFFu + ((u >> 16) & 1u);   // RNE
    return (unsigned short)(u >> 16);
}
__device__ __forceinline__ float bf2f(unsigned short h) {
    return __uint_as_float(((unsigned int)h) << 16);
}
__device__ __forceinline__ void gload_lds16(const unsigned short* g, unsigned short* l) {
    __builtin_amdgcn_global_load_lds(
        (const __attribute__((address_space(1))) unsigned int*)g,
        (__attribute__((address_space(3))) unsigned int*)l, 16, 0, 0);
}
__device__ __forceinline__ bf16x8 ldfrag(const unsigned short* p) {
    ushort8 t = *(const ushort8*)p;
    return __builtin_bit_cast(bf16x8, t);
}

// ---- small converters -------------------------------------------------
// dst[n*K + k] = bf16(src[k*N + n])   (transpose + convert)
__global__ void convT_kernel(const float* __restrict__ src, unsigned short* __restrict__ dst,
                             int K, int N) {
    int idx = blockIdx.x * 256 + threadIdx.x;
    int n = idx / K, k = idx - n * K;
    dst[idx] = f2bf(src[k * N + n]);
}
// flat convert, 4 elems/thread
__global__ void conv_kernel(const float* __restrict__ src, unsigned short* __restrict__ dst) {
    int i = blockIdx.x * 256 + threadIdx.x;
    float4 v = ((const float4*)src)[i];
    ushort4v r = { f2bf(v.x), f2bf(v.y), f2bf(v.z), f2bf(v.w) };
    ((ushort4v*)dst)[i] = r;
}

// ---- K1: Schi = S * sigmoid(context@W + B), bf16 out ------------------
// A = context fp32 [4096,512] (cvt in staging), B = W^T bf16 [256,512]
// tile 64x64, BK=32, 4 waves of 32x32
__launch_bounds__(256)
__global__ void k1_chi(const float* __restrict__ ctx, const unsigned short* __restrict__ WT,
                       const float* __restrict__ S, const float* __restrict__ Bb,
                       unsigned short* __restrict__ Schi) {
    __shared__ unsigned short As[64 * 32];
    __shared__ unsigned short Bs[64 * 32];
    int tid = threadIdx.x, w = tid >> 6, lane = tid & 63;
    int ln15 = lane & 15, quad = lane >> 4;
    int wr = w >> 1, wc = w & 1;
    int tm = blockIdx.y * 64, tn = blockIdx.x * 64;
    f32x4 acc[2][2] = {};
    int arow = tid >> 2, ac8 = (tid & 3) * 8;
    const float* ag = ctx + (size_t)(tm + arow) * N_CTX + ac8;
    int brow = (w << 4) + (lane >> 2), bc8 = (lane & 3) * 8;
    const unsigned short* bg = WT + (size_t)(tn + brow) * N_CTX + bc8;
    unsigned short* bl = Bs + brow * 32 + bc8;
    for (int k0 = 0; k0 < N_CTX; k0 += 32) {
        gload_lds16(bg + k0, bl);
        float4 v0 = *(const float4*)(ag + k0);
        float4 v1 = *(const float4*)(ag + k0 + 4);
        ushort8 a8 = { f2bf(v0.x), f2bf(v0.y), f2bf(v0.z), f2bf(v0.w),
                       f2bf(v1.x), f2bf(v1.y), f2bf(v1.z), f2bf(v1.w) };
        *(ushort8*)(As + tid * 8) = a8;
        __syncthreads();
        bf16x8 af[2], bfr[2];
        for (int i = 0; i < 2; i++) af[i]  = ldfrag(As + (wr * 32 + i * 16 + ln15) * 32 + quad * 8);
        for (int j = 0; j < 2; j++) bfr[j] = ldfrag(Bs + (wc * 32 + j * 16 + ln15) * 32 + quad * 8);
        for (int i = 0; i < 2; i++)
            for (int j = 0; j < 2; j++)
                acc[i][j] = __builtin_amdgcn_mfma_f32_16x16x32_bf16(af[i], bfr[j], acc[i][j], 0, 0, 0);
        __syncthreads();
    }
    for (int j = 0; j < 2; j++) {
        int col = tn + wc * 32 + j * 16 + ln15;
        float sv = S[col], bv = Bb[col];
        for (int i = 0; i < 2; i++)
            for (int r = 0; r < 4; r++) {
                int row = tm + wr * 32 + i * 16 + quad * 4 + r;
                float x = acc[i][j][r] + bv;
                float chi = sv / (1.f + __expf(-x));
                Schi[(size_t)row * RANK + col] = f2bf(chi);
            }
    }
}

// ---- K2: T0 += inputs@U (split-K, atomic fp32) ------------------------
// A = inputs fp32 [4096,4096] (cvt in staging), B = U^T bf16 [256,4096]
// tile 128x128, BK=32, k-chunk 512 (gridDim.z = 8)
__launch_bounds__(256)
__global__ void k2_t0(const float* __restrict__ X, const unsigned short* __restrict__ UT,
                      float* __restrict__ T0) {
    __shared__ unsigned short As[128 * 32];
    __shared__ unsigned short Bs[128 * 32];
    int tid = threadIdx.x, w = tid >> 6, lane = tid & 63;
    int ln15 = lane & 15, quad = lane >> 4;
    int wr = w >> 1, wc = w & 1;
    int tn = blockIdx.x * 128, tm = blockIdx.y * 128;
    int kbase = blockIdx.z * 512;
    f32x4 acc[4][4] = {};
    int arow = tid >> 2, ac8 = (tid & 3) * 8;
    const float* ag0 = X + (size_t)(tm + arow) * N_IN + kbase + ac8;
    const float* ag1 = ag0 + (size_t)64 * N_IN;
    int bq = lane >> 2, bc8 = (lane & 3) * 8;
    for (int kt = 0; kt < 16; kt++) {
        int k0 = kt * 32;
        for (int ib = 0; ib < 2; ib++) {
            int row = (w << 5) + (ib << 4) + bq;
            gload_lds16(UT + (size_t)(tn + row) * N_IN + kbase + k0 + bc8, Bs + row * 32 + bc8);
        }
        {
            float4 v0 = *(const float4*)(ag0 + k0);
            float4 v1 = *(const float4*)(ag0 + k0 + 4);
            ushort8 a8 = { f2bf(v0.x), f2bf(v0.y), f2bf(v0.z), f2bf(v0.w),
                           f2bf(v1.x), f2bf(v1.y), f2bf(v1.z), f2bf(v1.w) };
            *(ushort8*)(As + tid * 8) = a8;
            float4 u0 = *(const float4*)(ag1 + k0);
            float4 u1 = *(const float4*)(ag1 + k0 + 4);
            ushort8 b8 = { f2bf(u0.x), f2bf(u0.y), f2bf(u0.z), f2bf(u0.w),
                           f2bf(u1.x), f2bf(u1.y), f2bf(u1.z), f2bf(u1.w) };
            *(ushort8*)(As + 2048 + tid * 8) = b8;
        }
        __syncthreads();
        bf16x8 af[4], bfr[4];
        for (int i = 0; i < 4; i++) af[i]  = ldfrag(As + (wr * 64 + i * 16 + ln15) * 32 + quad * 8);
        for (int j = 0; j < 4; j++) bfr[j] = ldfrag(Bs + (wc * 64 + j * 16 + ln15) * 32 + quad * 8);
        for (int i = 0; i < 4; i++)
            for (int j = 0; j < 4; j++)
                acc[i][j] = __builtin_amdgcn_mfma_f32_16x16x32_bf16(af[i], bfr[j], acc[i][j], 0, 0, 0);
        __syncthreads();
    }
    for (int i = 0; i < 4; i++)
        for (int j = 0; j < 4; j++) {
            int col = tn + wc * 64 + j * 16 + ln15;
            for (int r = 0; r < 4; r++) {
                int row = tm + wr * 64 + i * 16 + quad * 4 + r;
                atomicAdd(&T0[(size_t)row * RANK + col], acc[i][j][r]);
            }
        }
}

// ---- E: T = bf16(T0 * Schi) -------------------------------------------
__global__ void e_mul(const float* __restrict__ T0, const unsigned short* __restrict__ Schi,
                      unsigned short* __restrict__ T) {
    int i = blockIdx.x * 256 + threadIdx.x;
    float4 t0 = ((const float4*)T0)[i];
    ushort4v sc = ((const ushort4v*)Schi)[i];
    ushort4v r = { f2bf(t0.x * bf2f(sc.x)), f2bf(t0.y * bf2f(sc.y)),
                   f2bf(t0.z * bf2f(sc.z)), f2bf(t0.w * bf2f(sc.w)) };
    ((ushort4v*)T)[i] = r;
}

// ---- K3: out = relu(T @ V^T + 2*bias) ---------------------------------
// A = T bf16 [4096,256], B = V bf16 [4096,256] (already [N,K] row-major)
// tile 128x128, BK=32, all-bf16 m97 structure
__launch_bounds__(256)
__global__ void k3_out(const unsigned short* __restrict__ T, const unsigned short* __restrict__ Vb,
                       const float* __restrict__ bias, float* __restrict__ out) {
    __shared__ unsigned short As[128 * 32];
    __shared__ unsigned short Bs[128 * 32];
    int tid = threadIdx.x, w = tid >> 6, lane = tid & 63;
    int ln15 = lane & 15, quad = lane >> 4;
    int wr = w >> 1, wc = w & 1;
    int tn = blockIdx.x * 128, tm = blockIdx.y * 128;
    f32x4 acc[4][4] = {};
    int bq = lane >> 2, c8 = (lane & 3) * 8;
    for (int kt = 0; kt < 8; kt++) {
        int k0 = kt * 32;
        for (int ib = 0; ib < 2; ib++) {
            int row = (w << 5) + (ib << 4) + bq;
            gload_lds16(T  + (size_t)(tm + row) * RANK + k0 + c8, As + row * 32 + c8);
            gload_lds16(Vb + (size_t)(tn + row) * RANK + k0 + c8, Bs + row * 32 + c8);
        }
        __syncthreads();
        bf16x8 af[4], bfr[4];
        for (int i = 0; i < 4; i++) af[i]  = ldfrag(As + (wr * 64 + i * 16 + ln15) * 32 + quad * 8);
        for (int j = 0; j < 4; j++) bfr[j] = ldfrag(Bs + (wc * 64 + j * 16 + ln15) * 32 + quad * 8);
        for (int i = 0; i < 4; i++)
            for (int j = 0; j < 4; j++)
                acc[i][j] = __builtin_amdgcn_mfma_f32_16x16x32_bf16(af[i], bfr[j], acc[i][j], 0, 0, 0);
        __syncthreads();
    }
    for (int j = 0; j < 4; j++) {
        int col = tn + wc * 64 + j * 16 + ln15;
        float bv = 2.f * bias[col];
        for (int i = 0; i < 4; i++)
            for (int r = 0; r < 4; r++) {
                int row = tm + wr * 64 + i * 16 + quad * 4 + r;
                float v = acc[i][j][r] + bv;
                out[(size_t)row * UNITS + col] = fmaxf(v, 0.f);
            }
    }
}

extern "C" void kernel_launch(void* const* d_in, const int* in_sizes, int n_in,
                              void* d_out, int out_size, void* d_ws, size_t ws_size,
                              hipStream_t stream) {
    (void)in_sizes; (void)n_in; (void)out_size; (void)ws_size;
    const float* inputs  = (const float*)d_in[0];
    const float* context = (const float*)d_in[1];
    const float* U       = (const float*)d_in[2];
    const float* S       = (const float*)d_in[3];
    const float* V       = (const float*)d_in[4];
    const float* W       = (const float*)d_in[5];
    const float* Bb      = (const float*)d_in[6];
    const float* bias    = (const float*)d_in[7];
    float* out = (float*)d_out;

    char* ws = (char*)d_ws;
    size_t o = 0;
    unsigned short* UT   = (unsigned short*)(ws + o); o += (size_t)RANK * N_IN * 2;   // 2 MiB
    unsigned short* WT   = (unsigned short*)(ws + o); o += (size_t)RANK * N_CTX * 2;  // 256 KiB
    unsigned short* Vb   = (unsigned short*)(ws + o); o += (size_t)UNITS * RANK * 2;  // 2 MiB
    unsigned short* Schi = (unsigned short*)(ws + o); o += (size_t)B_SZ * RANK * 2;   // 2 MiB
    float*          T0   = (float*)(ws + o);          o += (size_t)B_SZ * RANK * 4;   // 4 MiB
    unsigned short* T    = (unsigned short*)(ws + o); o += (size_t)B_SZ * RANK * 2;   // 2 MiB

    hipMemsetAsync(T0, 0, (size_t)B_SZ * RANK * sizeof(float), stream);

    convT_kernel<<<(RANK * N_IN) / 256, 256, 0, stream>>>(U, UT, N_IN, RANK);
    convT_kernel<<<(RANK * N_CTX) / 256, 256, 0, stream>>>(W, WT, N_CTX, RANK);
    conv_kernel<<<(UNITS * RANK) / (256 * 4), 256, 0, stream>>>(V, Vb);

    k1_chi<<<dim3(RANK / 64, B_SZ / 64), 256, 0, stream>>>(context, WT, S, Bb, Schi);
    k2_t0<<<dim3(RANK / 128, B_SZ / 128, 8), 256, 0, stream>>>(inputs, UT, T0);
    e_mul<<<(B_SZ * RANK) / (256 * 4), 256, 0, stream>>>(T0, Schi, T);
    k3_out<<<dim3(UNITS / 128, B_SZ / 128), 256, 0, stream>>>(T, Vb, bias, out);
}

// Round 2
// 185.650 us; speedup vs baseline: 1.1201x; 1.1201x over previous
//
#include <hip/hip_runtime.h>

#define B_SZ 4096
#define N_IN 4096
#define N_CTX 512
#define UNITS 4096
#define RANK 256
#define ZSPLIT 8

typedef __attribute__((ext_vector_type(8))) __bf16 bf16x8;
typedef __attribute__((ext_vector_type(4))) float f32x4;
typedef __attribute__((ext_vector_type(8))) unsigned short ushort8;
typedef __attribute__((ext_vector_type(4))) unsigned short ushort4v;

__device__ __forceinline__ unsigned short f2bf(float f) {
    unsigned int u = __float_as_uint(f);
    u += 0x7FFFu + ((u >> 16) & 1u);   // RNE
    return (unsigned short)(u >> 16);
}
__device__ __forceinline__ float bf2f(unsigned short h) {
    return __uint_as_float(((unsigned int)h) << 16);
}
__device__ __forceinline__ void gload_lds16(const unsigned short* g, unsigned short* l) {
    __builtin_amdgcn_global_load_lds(
        (const __attribute__((address_space(1))) unsigned int*)g,
        (__attribute__((address_space(3))) unsigned int*)l, 16, 0, 0);
}
__device__ __forceinline__ bf16x8 ldfrag(const unsigned short* p) {
    ushort8 t = *(const ushort8*)p;
    return __builtin_bit_cast(bf16x8, t);
}

// ---- coalesced tiled transpose+convert: src[R][C] fp32 -> dst[C][R] bf16 ----
__global__ void transpose_cvt(const float* __restrict__ src, unsigned short* __restrict__ dst,
                              int R, int C) {
    __shared__ unsigned short t[64][66];   // +2 pad breaks bank alignment
    int rb = blockIdx.x * 64, cb = blockIdx.y * 64;
    int tid = threadIdx.x;
    int r = tid >> 4, c4 = (tid & 15) * 4;
    for (int i = 0; i < 4; i++) {
        float4 v = *(const float4*)(src + (size_t)(rb + r + i * 16) * C + cb + c4);
        t[r + i * 16][c4 + 0] = f2bf(v.x);
        t[r + i * 16][c4 + 1] = f2bf(v.y);
        t[r + i * 16][c4 + 2] = f2bf(v.z);
        t[r + i * 16][c4 + 3] = f2bf(v.w);
    }
    __syncthreads();
    int c = tid >> 3, r8 = (tid & 7) * 8;
    for (int j = 0; j < 2; j++) {
        int cc = c + j * 32;
        ushort8 o;
        for (int k = 0; k < 8; k++) o[k] = t[r8 + k][cc];
        *(ushort8*)(dst + (size_t)(cb + cc) * R + rb + r8) = o;
    }
}

// flat convert fp32 -> bf16, 4 elems/thread
__global__ void conv_kernel(const float* __restrict__ src, unsigned short* __restrict__ dst) {
    int i = blockIdx.x * 256 + threadIdx.x;
    float4 v = ((const float4*)src)[i];
    ushort4v r = { f2bf(v.x), f2bf(v.y), f2bf(v.z), f2bf(v.w) };
    ((ushort4v*)dst)[i] = r;
}

// ---- K1: Schi = S * sigmoid(context@W + B), bf16 out ------------------
// tile 32x64, BK=64, grid (RANK/64, B_SZ/32) = (4,128) = 512 blocks
__launch_bounds__(256, 4)
__global__ void k1_chi(const float* __restrict__ ctx, const unsigned short* __restrict__ WT,
                       const float* __restrict__ S, const float* __restrict__ Bb,
                       unsigned short* __restrict__ Schi) {
    __shared__ unsigned short As[32 * 64];
    __shared__ unsigned short Bs[64 * 64];
    int tid = threadIdx.x, w = tid >> 6, lane = tid & 63;
    int ln15 = lane & 15, quad = lane >> 4;
    int wr = w >> 1, wc = w & 1;
    int tm = blockIdx.y * 32, tn = blockIdx.x * 64;
    f32x4 acc2[2] = {};
    int arow = tid >> 3, ac4 = (tid & 7) * 4;
    const float* ag = ctx + (size_t)(tm + arow) * N_CTX + ac4;
    int brow0 = w * 16, bl8 = lane >> 3, bk8 = (lane & 7) * 8;
    for (int kt = 0; kt < 8; kt++) {
        int k0 = kt * 64;
        for (int c = 0; c < 2; c++) {
            int row = brow0 + c * 8 + bl8;
            gload_lds16(WT + (size_t)(tn + row) * N_CTX + k0 + bk8, Bs + row * 64 + bk8);
        }
        for (int i = 0; i < 2; i++) {
            float4 v = *(const float4*)(ag + k0 + i * 32);
            ushort4v a4 = { f2bf(v.x), f2bf(v.y), f2bf(v.z), f2bf(v.w) };
            *(ushort4v*)(As + arow * 64 + ac4 + i * 32) = a4;
        }
        __syncthreads();
        for (int kh = 0; kh < 2; kh++) {
            bf16x8 af = ldfrag(As + (wr * 16 + ln15) * 64 + kh * 32 + quad * 8);
            for (int j = 0; j < 2; j++) {
                bf16x8 bfr = ldfrag(Bs + (wc * 32 + j * 16 + ln15) * 64 + kh * 32 + quad * 8);
                acc2[j] = __builtin_amdgcn_mfma_f32_16x16x32_bf16(af, bfr, acc2[j], 0, 0, 0);
            }
        }
        __syncthreads();
    }
    for (int j = 0; j < 2; j++) {
        int col = tn + wc * 32 + j * 16 + ln15;
        float sv = S[col], bv = Bb[col];
        for (int r = 0; r < 4; r++) {
            int row = tm + wr * 16 + quad * 4 + r;
            float x = acc2[j][r] + bv;
            float chi = sv / (1.f + __expf(-x));
            Schi[(size_t)row * RANK + col] = f2bf(chi);
        }
    }
}

// ---- K2: T0p[z] = inputs@U partial (split-K, bf16 partials, no atomics) ----
// tile 64x128, BK=64, grid (2, 64, 8) = 1024 blocks
__launch_bounds__(256, 4)
__global__ void k2_t0(const float* __restrict__ X, const unsigned short* __restrict__ UT,
                      unsigned short* __restrict__ T0p) {
    __shared__ unsigned short As[64 * 64];
    __shared__ unsigned short Bs[128 * 64];
    int tid = threadIdx.x, w = tid >> 6, lane = tid & 63;
    int ln15 = lane & 15, quad = lane >> 4;
    int wr = w >> 1, wc = w & 1;
    int tm = blockIdx.y * 64, tn = blockIdx.x * 128;
    int kbase = blockIdx.z * (N_IN / ZSPLIT);
    f32x4 acc[2][4] = {};
    int arow = tid >> 2, ac4 = (tid & 3) * 4;
    const float* ag = X + (size_t)(tm + arow) * N_IN + kbase + ac4;
    int brow0 = w * 32, bl8 = lane >> 3, bk8 = (lane & 7) * 8;
    for (int kt = 0; kt < (N_IN / ZSPLIT) / 64; kt++) {
        int k0 = kt * 64;
        for (int c = 0; c < 4; c++) {
            int row = brow0 + c * 8 + bl8;
            gload_lds16(UT + (size_t)(tn + row) * N_IN + kbase + k0 + bk8, Bs + row * 64 + bk8);
        }
        for (int i = 0; i < 4; i++) {
            float4 v = *(const float4*)(ag + k0 + i * 16);
            ushort4v a4 = { f2bf(v.x), f2bf(v.y), f2bf(v.z), f2bf(v.w) };
            *(ushort4v*)(As + arow * 64 + ac4 + i * 16) = a4;
        }
        __syncthreads();
        for (int kh = 0; kh < 2; kh++) {
            bf16x8 af[2], bfr[4];
            for (int i = 0; i < 2; i++)
                af[i] = ldfrag(As + (wr * 32 + i * 16 + ln15) * 64 + kh * 32 + quad * 8);
            for (int j = 0; j < 4; j++)
                bfr[j] = ldfrag(Bs + (wc * 64 + j * 16 + ln15) * 64 + kh * 32 + quad * 8);
            for (int i = 0; i < 2; i++)
                for (int j = 0; j < 4; j++)
                    acc[i][j] = __builtin_amdgcn_mfma_f32_16x16x32_bf16(af[i], bfr[j], acc[i][j], 0, 0, 0);
        }
        __syncthreads();
    }
    unsigned short* P = T0p + (size_t)blockIdx.z * B_SZ * RANK;
    for (int i = 0; i < 2; i++)
        for (int j = 0; j < 4; j++) {
            int col = tn + wc * 64 + j * 16 + ln15;
            for (int r = 0; r < 4; r++) {
                int row = tm + wr * 32 + i * 16 + quad * 4 + r;
                P[(size_t)row * RANK + col] = f2bf(acc[i][j][r]);
            }
        }
}

// ---- E: T = bf16( (sum_z T0p[z]) * Schi ) ------------------------------
__global__ void e_red(const unsigned short* __restrict__ T0p, const unsigned short* __restrict__ Schi,
                      unsigned short* __restrict__ T) {
    int i = blockIdx.x * 256 + threadIdx.x;   // ushort8 index
    const size_t stride = (size_t)B_SZ * RANK;
    float a[8] = {};
    for (int z = 0; z < ZSPLIT; z++) {
        ushort8 p = *(const ushort8*)(T0p + z * stride + (size_t)i * 8);
        for (int k = 0; k < 8; k++) a[k] += bf2f(p[k]);
    }
    ushort8 s = *(const ushort8*)(Schi + (size_t)i * 8);
    ushort8 o;
    for (int k = 0; k < 8; k++) o[k] = f2bf(a[k] * bf2f(s[k]));
    *(ushort8*)(T + (size_t)i * 8) = o;
}

// ---- K3: out = relu(T @ V^T + 2*bias) ---------------------------------
// tile 128x128, BK=64 (4 iters), grid (32,32) = 1024 blocks
__launch_bounds__(256, 3)
__global__ void k3_out(const unsigned short* __restrict__ T, const unsigned short* __restrict__ Vb,
                       const float* __restrict__ bias, float* __restrict__ out) {
    __shared__ unsigned short As[128 * 64];
    __shared__ unsigned short Bs[128 * 64];
    int tid = threadIdx.x, w = tid >> 6, lane = tid & 63;
    int ln15 = lane & 15, quad = lane >> 4;
    int wr = w >> 1, wc = w & 1;
    int tn = blockIdx.x * 128, tm = blockIdx.y * 128;
    f32x4 acc[4][4] = {};
    int row0 = w * 32, bl8 = lane >> 3, bk8 = (lane & 7) * 8;
    for (int kt = 0; kt < RANK / 64; kt++) {
        int k0 = kt * 64;
        for (int c = 0; c < 4; c++) {
            int row = row0 + c * 8 + bl8;
            gload_lds16(T  + (size_t)(tm + row) * RANK + k0 + bk8, As + row * 64 + bk8);
            gload_lds16(Vb + (size_t)(tn + row) * RANK + k0 + bk8, Bs + row * 64 + bk8);
        }
        __syncthreads();
        for (int kh = 0; kh < 2; kh++) {
            bf16x8 af[4], bfr[4];
            for (int i = 0; i < 4; i++)
                af[i] = ldfrag(As + (wr * 64 + i * 16 + ln15) * 64 + kh * 32 + quad * 8);
            for (int j = 0; j < 4; j++)
                bfr[j] = ldfrag(Bs + (wc * 64 + j * 16 + ln15) * 64 + kh * 32 + quad * 8);
            for (int i = 0; i < 4; i++)
                for (int j = 0; j < 4; j++)
                    acc[i][j] = __builtin_amdgcn_mfma_f32_16x16x32_bf16(af[i], bfr[j], acc[i][j], 0, 0, 0);
        }
        __syncthreads();
    }
    for (int j = 0; j < 4; j++) {
        int col = tn + wc * 64 + j * 16 + ln15;
        float bv = 2.f * bias[col];
        for (int i = 0; i < 4; i++)
            for (int r = 0; r < 4; r++) {
                int row = tm + wr * 64 + i * 16 + quad * 4 + r;
                float v = acc[i][j][r] + bv;
                out[(size_t)row * UNITS + col] = fmaxf(v, 0.f);
            }
    }
}

extern "C" void kernel_launch(void* const* d_in, const int* in_sizes, int n_in,
                              void* d_out, int out_size, void* d_ws, size_t ws_size,
                              hipStream_t stream) {
    (void)in_sizes; (void)n_in; (void)out_size; (void)ws_size;
    const float* inputs  = (const float*)d_in[0];
    const float* context = (const float*)d_in[1];
    const float* U       = (const float*)d_in[2];
    const float* S       = (const float*)d_in[3];
    const float* V       = (const float*)d_in[4];
    const float* W       = (const float*)d_in[5];
    const float* Bb      = (const float*)d_in[6];
    const float* bias    = (const float*)d_in[7];
    float* out = (float*)d_out;

    char* ws = (char*)d_ws;
    size_t o = 0;
    unsigned short* UT   = (unsigned short*)(ws + o); o += (size_t)RANK * N_IN * 2;          // 2 MiB
    unsigned short* WT   = (unsigned short*)(ws + o); o += (size_t)RANK * N_CTX * 2;         // 256 KiB
    unsigned short* Vb   = (unsigned short*)(ws + o); o += (size_t)UNITS * RANK * 2;         // 2 MiB
    unsigned short* Schi = (unsigned short*)(ws + o); o += (size_t)B_SZ * RANK * 2;          // 2 MiB
    unsigned short* T    = (unsigned short*)(ws + o); o += (size_t)B_SZ * RANK * 2;          // 2 MiB
    unsigned short* T0p  = (unsigned short*)(ws + o); o += (size_t)ZSPLIT * B_SZ * RANK * 2; // 16 MiB

    transpose_cvt<<<dim3(N_IN / 64, RANK / 64), 256, 0, stream>>>(U, UT, N_IN, RANK);
    transpose_cvt<<<dim3(N_CTX / 64, RANK / 64), 256, 0, stream>>>(W, WT, N_CTX, RANK);
    conv_kernel<<<(UNITS * RANK) / (256 * 4), 256, 0, stream>>>(V, Vb);

    k2_t0<<<dim3(RANK / 128, B_SZ / 64, ZSPLIT), 256, 0, stream>>>(inputs, UT, T0p);
    k1_chi<<<dim3(RANK / 64, B_SZ / 32), 256, 0, stream>>>(context, WT, S, Bb, Schi);
    e_red<<<(B_SZ * RANK) / (256 * 8), 256, 0, stream>>>(T0p, Schi, T);
    k3_out<<<dim3(UNITS / 128, B_SZ / 128), 256, 0, stream>>>(T, Vb, bias, out);
}

// Round 3
// 178.802 us; speedup vs baseline: 1.1630x; 1.0383x over previous
//
#include <hip/hip_runtime.h>

#define B_SZ 4096
#define N_IN 4096
#define N_CTX 512
#define UNITS 4096
#define RANK 256
#define ZSPLIT 8

typedef __attribute__((ext_vector_type(8))) __bf16 bf16x8;
typedef __attribute__((ext_vector_type(4))) float f32x4;
typedef __attribute__((ext_vector_type(8))) unsigned short ushort8;
typedef __attribute__((ext_vector_type(4))) unsigned short ushort4v;

__device__ __forceinline__ unsigned short f2bf(float f) {
    unsigned int u = __float_as_uint(f);
    u += 0x7FFFu + ((u >> 16) & 1u);   // RNE
    return (unsigned short)(u >> 16);
}
__device__ __forceinline__ float bf2f(unsigned short h) {
    return __uint_as_float(((unsigned int)h) << 16);
}
__device__ __forceinline__ void gload_lds16(const unsigned short* g, unsigned short* l) {
    __builtin_amdgcn_global_load_lds(
        (const __attribute__((address_space(1))) unsigned int*)g,
        (__attribute__((address_space(3))) unsigned int*)l, 16, 0, 0);
}
__device__ __forceinline__ bf16x8 ldfrag(const unsigned short* p) {
    ushort8 t = *(const ushort8*)p;
    return __builtin_bit_cast(bf16x8, t);
}

// ---- fused prep: U^T (bf16), W^T (bf16), V convert (bf16), one launch ----
// grid: 256 (U, 64x4 tiles) + 32 (W, 8x4 tiles) + 512 (V, 2048 elem/blk) = 800
__global__ void prep(const float* __restrict__ U, const float* __restrict__ W,
                     const float* __restrict__ V,
                     unsigned short* __restrict__ UT, unsigned short* __restrict__ WT,
                     unsigned short* __restrict__ Vb) {
    __shared__ unsigned short t[64][66];
    int bid = blockIdx.x, tid = threadIdx.x;
    if (bid < 288) {
        const float* src; unsigned short* dst; int R, C, rb, cb;
        if (bid < 256) { src = U; dst = UT; R = N_IN; C = RANK; rb = (bid & 63) * 64; cb = (bid >> 6) * 64; }
        else { int b = bid - 256; src = W; dst = WT; R = N_CTX; C = RANK; rb = (b & 7) * 64; cb = (b >> 3) * 64; }
        int r = tid >> 4, c4 = (tid & 15) * 4;
        for (int i = 0; i < 4; i++) {
            float4 v = *(const float4*)(src + (size_t)(rb + r + i * 16) * C + cb + c4);
            t[r + i * 16][c4 + 0] = f2bf(v.x);
            t[r + i * 16][c4 + 1] = f2bf(v.y);
            t[r + i * 16][c4 + 2] = f2bf(v.z);
            t[r + i * 16][c4 + 3] = f2bf(v.w);
        }
        __syncthreads();
        int c = tid >> 3, r8 = (tid & 7) * 8;
        for (int j = 0; j < 2; j++) {
            int cc = c + j * 32;
            ushort8 o;
            for (int k = 0; k < 8; k++) o[k] = t[r8 + k][cc];
            *(ushort8*)(dst + (size_t)(cb + cc) * R + rb + r8) = o;
        }
    } else {
        size_t base = (size_t)(bid - 288) * 2048 + (size_t)tid * 8;
        float4 a = *(const float4*)(V + base);
        float4 b = *(const float4*)(V + base + 4);
        ushort8 o = { f2bf(a.x), f2bf(a.y), f2bf(a.z), f2bf(a.w),
                      f2bf(b.x), f2bf(b.y), f2bf(b.z), f2bf(b.w) };
        *(ushort8*)(Vb + base) = o;
    }
}

// All GEMM tiles: rows of 64 bf16 = 128B = 8 chunks of 16B.
// LDS slot (row, cs) holds data chunk cs^(row&7)  -> bank-balanced b128 access.

// ---- K1: Schi = S * sigmoid(context@W + B), bf16 out ------------------
// tile 32x64, BK=64, grid (4,128) = 512 blocks
__launch_bounds__(256, 4)
__global__ void k1_chi(const float* __restrict__ ctx, const unsigned short* __restrict__ WT,
                       const float* __restrict__ S, const float* __restrict__ Bb,
                       unsigned short* __restrict__ Schi) {
    __shared__ unsigned short As[32 * 64];
    __shared__ unsigned short Bs[64 * 64];
    int tid = threadIdx.x, w = tid >> 6, lane = tid & 63;
    int ln15 = lane & 15, quad = lane >> 4;
    int wr = w >> 1, wc = w & 1;
    int tm = blockIdx.y * 32, tn = blockIdx.x * 64;
    f32x4 acc2[2] = {};
    int arow = tid >> 3, acs = tid & 7;                 // A: 1 chunk/thread
    const float* ag = ctx + (size_t)(tm + arow) * N_CTX + acs * 8;
    unsigned short* al = As + arow * 64 + (acs ^ (arow & 7)) * 8;
    int bl8 = lane >> 3, bcs = lane & 7;
    int bgc = (bcs ^ bl8) * 8;                          // swizzled global chunk for B
    for (int kt = 0; kt < 8; kt++) {
        int k0 = kt * 64;
        for (int c = 0; c < 2; c++) {
            int row = w * 16 + c * 8 + bl8;
            gload_lds16(WT + (size_t)(tn + row) * N_CTX + k0 + bgc, Bs + row * 64 + bcs * 8);
        }
        {
            float4 v0 = *(const float4*)(ag + k0);
            float4 v1 = *(const float4*)(ag + k0 + 4);
            ushort8 a8 = { f2bf(v0.x), f2bf(v0.y), f2bf(v0.z), f2bf(v0.w),
                           f2bf(v1.x), f2bf(v1.y), f2bf(v1.z), f2bf(v1.w) };
            *(ushort8*)al = a8;
        }
        __syncthreads();
        for (int kh = 0; kh < 2; kh++) {
            int ch = kh * 4 + quad;
            bf16x8 af = ldfrag(As + (wr * 16 + ln15) * 64 + (ch ^ (ln15 & 7)) * 8);
            for (int j = 0; j < 2; j++) {
                int row = wc * 32 + j * 16 + ln15;
                bf16x8 bfr = ldfrag(Bs + row * 64 + (ch ^ (ln15 & 7)) * 8);
                acc2[j] = __builtin_amdgcn_mfma_f32_16x16x32_bf16(af, bfr, acc2[j], 0, 0, 0);
            }
        }
        __syncthreads();
    }
    for (int j = 0; j < 2; j++) {
        int col = tn + wc * 32 + j * 16 + ln15;
        float sv = S[col], bv = Bb[col];
        for (int r = 0; r < 4; r++) {
            int row = tm + wr * 16 + quad * 4 + r;
            float x = acc2[j][r] + bv;
            float chi = sv / (1.f + __expf(-x));
            Schi[(size_t)row * RANK + col] = f2bf(chi);
        }
    }
}

// ---- K2: T0p[z] = inputs@U partial (split-K, bf16 partials) -----------
// tile 64x128, BK=64, grid (2, 64, 8) = 1024 blocks
__launch_bounds__(256, 4)
__global__ void k2_t0(const float* __restrict__ X, const unsigned short* __restrict__ UT,
                      unsigned short* __restrict__ T0p) {
    __shared__ unsigned short As[64 * 64];
    __shared__ unsigned short Bs[128 * 64];
    int tid = threadIdx.x, w = tid >> 6, lane = tid & 63;
    int ln15 = lane & 15, quad = lane >> 4;
    int wr = w >> 1, wc = w & 1;
    int tm = blockIdx.y * 64, tn = blockIdx.x * 128;
    int kbase = blockIdx.z * (N_IN / ZSPLIT);
    f32x4 acc[2][4] = {};
    int arow = tid >> 2, acs0 = tid & 3;                // A: 2 chunks/thread (cs0, cs0+4)
    const float* ag = X + (size_t)(tm + arow) * N_IN + kbase;
    unsigned short* al0 = As + arow * 64 + ((acs0 + 0) ^ (arow & 7)) * 8;
    unsigned short* al1 = As + arow * 64 + ((acs0 + 4) ^ (arow & 7)) * 8;
    int bl8 = lane >> 3, bcs = lane & 7;
    int bgc = (bcs ^ bl8) * 8;
    for (int kt = 0; kt < (N_IN / ZSPLIT) / 64; kt++) {
        int k0 = kt * 64;
        for (int c = 0; c < 4; c++) {
            int row = w * 32 + c * 8 + bl8;
            gload_lds16(UT + (size_t)(tn + row) * N_IN + kbase + k0 + bgc, Bs + row * 64 + bcs * 8);
        }
        {
            float4 v0 = *(const float4*)(ag + k0 + acs0 * 8);
            float4 v1 = *(const float4*)(ag + k0 + acs0 * 8 + 4);
            float4 u0 = *(const float4*)(ag + k0 + (acs0 + 4) * 8);
            float4 u1 = *(const float4*)(ag + k0 + (acs0 + 4) * 8 + 4);
            ushort8 a8 = { f2bf(v0.x), f2bf(v0.y), f2bf(v0.z), f2bf(v0.w),
                           f2bf(v1.x), f2bf(v1.y), f2bf(v1.z), f2bf(v1.w) };
            ushort8 b8 = { f2bf(u0.x), f2bf(u0.y), f2bf(u0.z), f2bf(u0.w),
                           f2bf(u1.x), f2bf(u1.y), f2bf(u1.z), f2bf(u1.w) };
            *(ushort8*)al0 = a8;
            *(ushort8*)al1 = b8;
        }
        __syncthreads();
        for (int kh = 0; kh < 2; kh++) {
            int ch = kh * 4 + quad;
            int sw = (ch ^ (ln15 & 7)) * 8;
            bf16x8 af[2], bfr[4];
            for (int i = 0; i < 2; i++)
                af[i] = ldfrag(As + (wr * 32 + i * 16 + ln15) * 64 + sw);
            for (int j = 0; j < 4; j++)
                bfr[j] = ldfrag(Bs + (wc * 64 + j * 16 + ln15) * 64 + sw);
            for (int i = 0; i < 2; i++)
                for (int j = 0; j < 4; j++)
                    acc[i][j] = __builtin_amdgcn_mfma_f32_16x16x32_bf16(af[i], bfr[j], acc[i][j], 0, 0, 0);
        }
        __syncthreads();
    }
    unsigned short* P = T0p + (size_t)blockIdx.z * B_SZ * RANK;
    for (int i = 0; i < 2; i++)
        for (int j = 0; j < 4; j++) {
            int col = tn + wc * 64 + j * 16 + ln15;
            for (int r = 0; r < 4; r++) {
                int row = tm + wr * 32 + i * 16 + quad * 4 + r;
                P[(size_t)row * RANK + col] = f2bf(acc[i][j][r]);
            }
        }
}

// ---- E: T = bf16( (sum_z T0p[z]) * Schi ) ------------------------------
__global__ void e_red(const unsigned short* __restrict__ T0p, const unsigned short* __restrict__ Schi,
                      unsigned short* __restrict__ T) {
    int i = blockIdx.x * 256 + threadIdx.x;   // ushort8 index
    const size_t stride = (size_t)B_SZ * RANK;
    float a[8] = {};
    for (int z = 0; z < ZSPLIT; z++) {
        ushort8 p = *(const ushort8*)(T0p + z * stride + (size_t)i * 8);
        for (int k = 0; k < 8; k++) a[k] += bf2f(p[k]);
    }
    ushort8 s = *(const ushort8*)(Schi + (size_t)i * 8);
    ushort8 o;
    for (int k = 0; k < 8; k++) o[k] = f2bf(a[k] * bf2f(s[k]));
    *(ushort8*)(T + (size_t)i * 8) = o;
}

// ---- K3: out = relu(T @ V^T + 2*bias) ---------------------------------
// tile 64x128 (m x n), BK=64 (4 iters), grid (32, 64) = 2048 blocks
__launch_bounds__(256, 4)
__global__ void k3_out(const unsigned short* __restrict__ T, const unsigned short* __restrict__ Vb,
                       const float* __restrict__ bias, float* __restrict__ out) {
    __shared__ unsigned short As[64 * 64];
    __shared__ unsigned short Bs[128 * 64];
    int tid = threadIdx.x, w = tid >> 6, lane = tid & 63;
    int ln15 = lane & 15, quad = lane >> 4;
    int wr = w >> 1, wc = w & 1;
    int tn = blockIdx.x * 128, tm = blockIdx.y * 64;
    f32x4 acc[2][4] = {};
    int bl8 = lane >> 3, bcs = lane & 7;
    int bgc = (bcs ^ bl8) * 8;
    for (int kt = 0; kt < RANK / 64; kt++) {
        int k0 = kt * 64;
        for (int c = 0; c < 2; c++) {
            int row = w * 16 + c * 8 + bl8;
            gload_lds16(T + (size_t)(tm + row) * RANK + k0 + bgc, As + row * 64 + bcs * 8);
        }
        for (int c = 0; c < 4; c++) {
            int row = w * 32 + c * 8 + bl8;
            gload_lds16(Vb + (size_t)(tn + row) * RANK + k0 + bgc, Bs + row * 64 + bcs * 8);
        }
        __syncthreads();
        for (int kh = 0; kh < 2; kh++) {
            int ch = kh * 4 + quad;
            int sw = (ch ^ (ln15 & 7)) * 8;
            bf16x8 af[2], bfr[4];
            for (int i = 0; i < 2; i++)
                af[i] = ldfrag(As + (wr * 32 + i * 16 + ln15) * 64 + sw);
            for (int j = 0; j < 4; j++)
                bfr[j] = ldfrag(Bs + (wc * 64 + j * 16 + ln15) * 64 + sw);
            for (int i = 0; i < 2; i++)
                for (int j = 0; j < 4; j++)
                    acc[i][j] = __builtin_amdgcn_mfma_f32_16x16x32_bf16(af[i], bfr[j], acc[i][j], 0, 0, 0);
        }
        __syncthreads();
    }
    for (int j = 0; j < 4; j++) {
        int col = tn + wc * 64 + j * 16 + ln15;
        float bv = 2.f * bias[col];
        for (int i = 0; i < 2; i++)
            for (int r = 0; r < 4; r++) {
                int row = tm + wr * 32 + i * 16 + quad * 4 + r;
                float v = acc[i][j][r] + bv;
                out[(size_t)row * UNITS + col] = fmaxf(v, 0.f);
            }
    }
}

extern "C" void kernel_launch(void* const* d_in, const int* in_sizes, int n_in,
                              void* d_out, int out_size, void* d_ws, size_t ws_size,
                              hipStream_t stream) {
    (void)in_sizes; (void)n_in; (void)out_size; (void)ws_size;
    const float* inputs  = (const float*)d_in[0];
    const float* context = (const float*)d_in[1];
    const float* U       = (const float*)d_in[2];
    const float* S       = (const float*)d_in[3];
    const float* V       = (const float*)d_in[4];
    const float* W       = (const float*)d_in[5];
    const float* Bb      = (const float*)d_in[6];
    const float* bias    = (const float*)d_in[7];
    float* out = (float*)d_out;

    char* ws = (char*)d_ws;
    size_t o = 0;
    unsigned short* UT   = (unsigned short*)(ws + o); o += (size_t)RANK * N_IN * 2;
    unsigned short* WT   = (unsigned short*)(ws + o); o += (size_t)RANK * N_CTX * 2;
    unsigned short* Vb   = (unsigned short*)(ws + o); o += (size_t)UNITS * RANK * 2;
    unsigned short* Schi = (unsigned short*)(ws + o); o += (size_t)B_SZ * RANK * 2;
    unsigned short* T    = (unsigned short*)(ws + o); o += (size_t)B_SZ * RANK * 2;
    unsigned short* T0p  = (unsigned short*)(ws + o); o += (size_t)ZSPLIT * B_SZ * RANK * 2;

    prep<<<800, 256, 0, stream>>>(U, W, V, UT, WT, Vb);
    k2_t0<<<dim3(RANK / 128, B_SZ / 64, ZSPLIT), 256, 0, stream>>>(inputs, UT, T0p);
    k1_chi<<<dim3(RANK / 64, B_SZ / 32), 256, 0, stream>>>(context, WT, S, Bb, Schi);
    e_red<<<(B_SZ * RANK) / (256 * 8), 256, 0, stream>>>(T0p, Schi, T);
    k3_out<<<dim3(UNITS / 128, B_SZ / 64), 256, 0, stream>>>(T, Vb, bias, out);
}